// Round 9
// baseline (244.392 us; speedup 1.0000x reference)
//
#include <hip/hip_runtime.h>
#include <math.h>

// Problem: B=4, S=1024, F=256, H=8, FH=2048. SCALE=16 (multiplies logits).
#define SQ 1024
#define FQ 256
#define FH 2048

typedef _Float16 f16;
typedef f16  f16x8 __attribute__((ext_vector_type(8)));
typedef float f32x4 __attribute__((ext_vector_type(4)));

// Async global->LDS, 16 B/lane. LDS dest = wave-uniform base + lane*16.
#define GLOAD_LDS16(gp, lp) \
    __builtin_amdgcn_global_load_lds((const __attribute__((address_space(1))) void*)(gp), \
                                     (__attribute__((address_space(3))) void*)(lp), 16, 0, 0)

// LDS-only barrier: waits LDS ops, does NOT drain in-flight global loads
// (unlike __syncthreads, which emits s_waitcnt vmcnt(0) before s_barrier).
// Safe when all cross-wave communication is through LDS.
#define LGKM_BARRIER() asm volatile("s_waitcnt lgkmcnt(0)\ns_barrier" ::: "memory")

// ---------------------------------------------------------------------------
// fp32 -> f16 convert (x input).
// ---------------------------------------------------------------------------
__global__ __launch_bounds__(256) void cvt_kernel(const float* __restrict__ in,
                                                  f16* __restrict__ out) {
    int idx = (blockIdx.x * 256 + threadIdx.x) * 4;
    float4 v = *(const float4*)(in + idx);
    out[idx + 0] = (f16)v.x; out[idx + 1] = (f16)v.y;
    out[idx + 2] = (f16)v.z; out[idx + 3] = (f16)v.w;
}

// ---------------------------------------------------------------------------
// Transpose+convert W (256 x 2048 fp32) -> WT (2048 x 256 f16). z picks matrix.
// ---------------------------------------------------------------------------
__global__ __launch_bounds__(256) void transpose_qkv(const float* __restrict__ W0,
                                                     const float* __restrict__ W1,
                                                     const float* __restrict__ W2,
                                                     f16* __restrict__ T0,
                                                     f16* __restrict__ T1,
                                                     f16* __restrict__ T2) {
    const float* W = blockIdx.z == 0 ? W0 : (blockIdx.z == 1 ? W1 : W2);
    f16* WT        = blockIdx.z == 0 ? T0 : (blockIdx.z == 1 ? T1 : T2);
    __shared__ f16 T[32][33];
    const int tx = threadIdx.x & 31, ty = threadIdx.x >> 5;
    const int n0 = blockIdx.x * 32, k0 = blockIdx.y * 32;
#pragma unroll
    for (int i = 0; i < 4; ++i)
        T[ty + i * 8][tx] = (f16)W[(size_t)(k0 + ty + i * 8) * FH + n0 + tx];
    __syncthreads();
#pragma unroll
    for (int i = 0; i < 4; ++i)
        WT[(size_t)(n0 + ty + i * 8) * FQ + k0 + tx] = T[tx][ty + i * 8];
}

// ---------------------------------------------------------------------------
// Wo (2048 x 256 fp32, row fh = f*8+h) -> WoT (256 x 2048 f16) with k
// PERMUTED to h*256+f (matches WV layout). grid (8 n-tiles, 64 = ft*8+h).
// ---------------------------------------------------------------------------
__global__ __launch_bounds__(256) void transpose_wo(const float* __restrict__ W,
                                                    f16* __restrict__ WT) {
    __shared__ f16 T[32][33];
    const int tx = threadIdx.x & 31, ty = threadIdx.x >> 5;
    const int n0 = blockIdx.x * 32;
    const int ft = blockIdx.y >> 3, h = blockIdx.y & 7;
#pragma unroll
    for (int i = 0; i < 4; ++i) {
        int fl = ty + i * 8;
        T[fl][tx] = (f16)W[(size_t)((ft * 32 + fl) * 8 + h) * FQ + n0 + tx];
    }
    __syncthreads();
#pragma unroll
    for (int i = 0; i < 4; ++i)
        WT[(size_t)(n0 + ty + i * 8) * FH + h * 256 + ft * 32 + tx] = T[tx][ty + i * 8];
}

// ---------------------------------------------------------------------------
// Swizzled staging, LDS row stride 64 f16 (128 B): 8 rows/inst, logical
// granule g (0..7) stored at physical slot g^(row&7).
// ---------------------------------------------------------------------------
__device__ __forceinline__ void stage_sw64(const f16* __restrict__ G, int ldg,
                                           int row0, int c0, f16* S,
                                           int nrows, int w, int lane) {
    const int rsub = lane >> 3;           // 0..7
    const int g    = (lane & 7) ^ (rsub & 7);
#pragma unroll
    for (int rI = w; rI < (nrows >> 3); rI += 4) {
        GLOAD_LDS16(G + (size_t)(row0 + rI * 8 + rsub) * ldg + c0 + g * 8,
                    S + rI * 512);
    }
}

// ---------------------------------------------------------------------------
// 128x128 MFMA tile, BK=64 swizzled staging. 4 waves 2x2 of 64x64.
// ---------------------------------------------------------------------------
__device__ __forceinline__ void gemm128_sw(const f16* __restrict__ A, int lda,
                                           const f16* __restrict__ Bt, int ldb,
                                           int kbeg, int kend, f16* As, f16* Bs,
                                           f32x4 acc[4][4], int row0, int col0) {
    const int t = threadIdx.x, lane = t & 63, w = t >> 6;
    const int wr = w >> 1, wc = w & 1;
    const int lrow = lane & 15, quad = lane >> 4;
    for (int k0 = kbeg; k0 < kend; k0 += 64) {
        __syncthreads();
        stage_sw64(A, lda, row0, k0, As, 128, w, lane);
        stage_sw64(Bt, ldb, col0, k0, Bs, 128, w, lane);
        __syncthreads();
#pragma unroll
        for (int kk = 0; kk < 2; ++kk) {
            f16x8 af[4], bf[4];
#pragma unroll
            for (int i = 0; i < 4; ++i) {
                int r = wr * 64 + i * 16 + lrow;
                af[i] = *(const f16x8*)&As[r * 64 + (((kk * 4 + quad) ^ (r & 7)) << 3)];
            }
#pragma unroll
            for (int j = 0; j < 4; ++j) {
                int r = wc * 64 + j * 16 + lrow;
                bf[j] = *(const f16x8*)&Bs[r * 64 + (((kk * 4 + quad) ^ (r & 7)) << 3)];
            }
#pragma unroll
            for (int i = 0; i < 4; ++i)
#pragma unroll
                for (int j = 0; j < 4; ++j)
                    acc[i][j] = __builtin_amdgcn_mfma_f32_16x16x32_f16(af[i], bf[j], acc[i][j], 0, 0, 0);
        }
    }
}

// ---------------------------------------------------------------------------
// Merged QKV projection with coalesced LDS-roundtrip epilogue.
// z=0 Q -> (b,h,s,f); z=1 K -> (b,h,s,f); z=2 V -> (b,h,f,s).
// ---------------------------------------------------------------------------
__global__ __launch_bounds__(256) void proj_mfma(const f16* __restrict__ xh,
                                                 const f16* __restrict__ wqT,
                                                 const f16* __restrict__ wkT,
                                                 const f16* __restrict__ wvT,
                                                 f16* __restrict__ qb,
                                                 f16* __restrict__ kb,
                                                 f16* __restrict__ vb) {
    const int z = blockIdx.z;
    const f16* WT = z == 0 ? wqT : (z == 1 ? wkT : wvT);
    f16* O        = z == 0 ? qb  : (z == 1 ? kb  : vb);
    __shared__ f16 smem[17408];          // As|Bs (16384) ; Es (17408) alias
    f16* As = smem;
    f16* Bs = smem + 8192;
    f32x4 acc[4][4] = {};
    const int row0 = blockIdx.y * 128, col0 = blockIdx.x * 128;
    gemm128_sw(xh, FQ, WT, FQ, 0, FQ, As, Bs, acc, row0, col0);

    __syncthreads();                     // As/Bs dead -> reuse as Es
    f16* Es = smem;                      // ld 136
    const int lane = threadIdx.x & 63, w = threadIdx.x >> 6;
    const int wr = w >> 1, wc = w & 1;
    const int lrow = lane & 15, quad = lane >> 4;
    if (z != 2) {
#pragma unroll
        for (int i = 0; i < 4; ++i)
#pragma unroll
            for (int rr = 0; rr < 4; ++rr) {
                int rl = 64 * wr + 16 * i + 4 * quad + rr;
#pragma unroll
                for (int j = 0; j < 4; ++j) {
                    int cc = 64 * wc + 16 * j + lrow;
                    Es[rl * 136 + (cc & 7) * 16 + (cc >> 3)] = (f16)acc[i][j][rr];
                }
            }
        __syncthreads();
        const int f0 = col0 >> 3;
#pragma unroll
        for (int it = 0; it < 4; ++it) {
            int c = it * 256 + threadIdx.x;
            int row = c >> 3, hh = c & 7;
            int gr = row0 + row, bbb = gr >> 10, s = gr & 1023;
            f16x8 v0 = *(const f16x8*)&Es[row * 136 + hh * 16];
            f16x8 v1 = *(const f16x8*)&Es[row * 136 + hh * 16 + 8];
            f16* dst = O + ((size_t)(bbb * 8 + hh) * SQ + s) * FQ + f0;
            *(f16x8*)dst = v0;
            *(f16x8*)(dst + 8) = v1;
        }
    } else {
#pragma unroll
        for (int i = 0; i < 4; ++i)
#pragma unroll
            for (int rr = 0; rr < 4; ++rr) {
                int rl = 64 * wr + 16 * i + 4 * quad + rr;
#pragma unroll
                for (int j = 0; j < 4; ++j) {
                    int cc = 64 * wc + 16 * j + lrow;
                    Es[cc * 136 + rl] = (f16)acc[i][j][rr];
                }
            }
        __syncthreads();
        const int bbb = row0 >> 10, s0 = row0 & 1023;
#pragma unroll
        for (int it = 0; it < 8; ++it) {
            int c = it * 256 + threadIdx.x;
            int cc = c >> 4, sc = c & 15;
            int hh = cc & 7, f = (col0 >> 3) + (cc >> 3);
            f16x8 v = *(const f16x8*)&Es[cc * 136 + sc * 8];
            *(f16x8*)(O + ((size_t)(bbb * 8 + hh) * FQ + f) * SQ + s0 + sc * 8) = v;
        }
    }
}

// ---------------------------------------------------------------------------
// Fused attention v6 — drain-free pipeline. Per block: 64 Q-rows of (b,h).
// j-tile = 32 (32 iterations). Waves 2x2: wr = 32-row half, wc = col half.
//  - Q strip in registers (qf, loaded once).
//  - K tile double-buffered in LDS via REGISTER roundtrip: kreg holds jt+1
//    data, ds_written at top of jt; kreg then loads jt+2 (full-iter cover).
//  - V fragments in registers, loaded at top, consumed in PV (~QK-phase
//    cover); they survive the barriers because barriers are LGKM-only.
//  - P transform via padded LDS scratch; 2 lgkm-barriers/jt, no vmcnt drains.
// LDS: Kdb 2x(32x258) + Pscr 64x34 = 37376 B -> 2 blocks/CU (VGPR-capped).
// ---------------------------------------------------------------------------
__global__ __launch_bounds__(256, 2) void fused_attn(const f16* __restrict__ Qb,
                                                     const f16* __restrict__ Kb,
                                                     const f16* __restrict__ Vt,
                                                     f16* __restrict__ WV) {
    __shared__ f16 smem[18688];          // Kbuf0 8256 | Kbuf1 8256 | Pscr 2176
    f16* Kbuf0 = smem;                   // 32 x 258
    f16* Kbuf1 = smem + 8256;
    f16* Pscr  = smem + 16512;           // 64 x 34
    const int t = threadIdx.x, lane = t & 63, w = t >> 6;
    const int wr = w >> 1, wc = w & 1;
    const int lrow = lane & 15, quad = lane >> 4;
    // XCD swizzle: 4 consecutive heads per XCD -> Q/K/V L2-resident per XCD.
    const int n = blockIdx.x;
    const int xcd = n & 7, rest = n >> 3;
    const int bh = xcd * 4 + (rest & 3);
    const int strip = rest >> 2;                 // 0..15
    const int m0 = strip * 64;
    const int bb = bh >> 3, h = bh & 7;
    const f16* Qg = Qb + (size_t)bh * SQ * FQ;   // (s,f)
    const f16* Kg = Kb + (size_t)bh * SQ * FQ;   // (s,f)
    const f16* Vg = Vt + (size_t)bh * FQ * SQ;   // (f,s)

    // Q rows [m0+32wr, +32) as A-fragments in registers (loaded once).
    f16x8 qf[2][8];
#pragma unroll
    for (int mi = 0; mi < 2; ++mi)
#pragma unroll
        for (int ks = 0; ks < 8; ++ks)
            qf[mi][ks] = *(const f16x8*)(Qg + (size_t)(m0 + 32 * wr + 16 * mi + lrow) * FQ
                                             + ks * 32 + quad * 8);

    // K staging geometry: per wave 4 insts, each 2 rows x 32 granules.
    const int krow = w * 8 + (lane >> 5);        // + i*2
    const int kgr  = lane & 31;

    f32x4 acc_o[2][8] = {};   // rows 32wr+16mi(+4quad+rr), f = 128wc+16nj+lrow
    f16x8 kreg[4], vf[8];

    // Prologue: K(jt0) -> Kbuf0; prefetch K(jt1) into kreg.
#pragma unroll
    for (int i = 0; i < 4; ++i)
        kreg[i] = *(const f16x8*)(Kg + (size_t)(krow + i * 2) * FQ + kgr * 8);
#pragma unroll
    for (int i = 0; i < 4; ++i)
        *(f16x8*)&Kbuf0[(krow + i * 2) * 258 + kgr * 8] = kreg[i];
#pragma unroll
    for (int i = 0; i < 4; ++i)
        kreg[i] = *(const f16x8*)(Kg + (size_t)(32 + krow + i * 2) * FQ + kgr * 8);
    LGKM_BARRIER();

    for (int jt = 0; jt < 32; ++jt) {
        const int j0 = jt * 32;
        f16* KB  = (jt & 1) ? Kbuf1 : Kbuf0;
        f16* KBn = (jt & 1) ? Kbuf0 : Kbuf1;
        // ---- top: V frags for THIS tile (consumed after mid-barrier) ----
#pragma unroll
        for (int nj = 0; nj < 8; ++nj)
            vf[nj] = *(const f16x8*)(Vg + (size_t)(128 * wc + 16 * nj + lrow) * SQ
                                         + j0 + quad * 8);
        // ---- top: ds_write K(jt+1) from kreg; then load K(jt+2) ----
        if (jt < 31) {
#pragma unroll
            for (int i = 0; i < 4; ++i)
                *(f16x8*)&KBn[(krow + i * 2) * 258 + kgr * 8] = kreg[i];
        }
        if (jt < 30) {
#pragma unroll
            for (int i = 0; i < 4; ++i)
                kreg[i] = *(const f16x8*)(Kg + (size_t)(j0 + 64 + krow + i * 2) * FQ + kgr * 8);
        }
        // ---- QK^T: S rows 32wr..+32, cols 16wc..+16, K from KB ----
        f32x4 acc_s[2] = {};
#pragma unroll
        for (int ks = 0; ks < 8; ++ks) {
            f16x8 bf = *(const f16x8*)&KB[(16 * wc + lrow) * 258 + (ks * 4 + quad) * 8];
#pragma unroll
            for (int mi = 0; mi < 2; ++mi)
                acc_s[mi] = __builtin_amdgcn_mfma_f32_16x16x32_f16(qf[mi][ks], bf, acc_s[mi], 0, 0, 0);
        }
        // ---- sigmoid -> Pscr (cross-wave: wc halves complete each other) ----
#pragma unroll
        for (int mi = 0; mi < 2; ++mi)
#pragma unroll
            for (int rr = 0; rr < 4; ++rr)
                Pscr[(32 * wr + 16 * mi + 4 * quad + rr) * 34 + 16 * wc + lrow] =
                    (f16)(1.0f / (1.0f + __expf(-16.0f * acc_s[mi][rr])));
        LGKM_BARRIER();                  // Pscr visible; vf/kreg loads survive
        // ---- PV: rows 32wr..+32 x f 128wc..+128; V from vf regs ----
        f16x8 ap[2];
#pragma unroll
        for (int mi = 0; mi < 2; ++mi)
            ap[mi] = *(const f16x8*)&Pscr[(32 * wr + 16 * mi + lrow) * 34 + quad * 8];
#pragma unroll
        for (int nj = 0; nj < 8; ++nj)
#pragma unroll
            for (int mi = 0; mi < 2; ++mi)
                acc_o[mi][nj] = __builtin_amdgcn_mfma_f32_16x16x32_f16(
                    ap[mi], vf[nj], acc_o[mi][nj], 0, 0, 0);
        LGKM_BARRIER();                  // KB reads done / Pscr WAR for next jt
    }
    // ---- epilogue: LDS roundtrip -> 512 B contiguous rows ----
    __syncthreads();                             // smem dead
    f16* Es = smem;                              // 64 x 264 (16896 <= 18688)
#pragma unroll
    for (int mi = 0; mi < 2; ++mi)
#pragma unroll
        for (int nj = 0; nj < 8; ++nj)
#pragma unroll
            for (int rr = 0; rr < 4; ++rr)
                Es[(32 * wr + 16 * mi + 4 * quad + rr) * 264 + 128 * wc + 16 * nj + lrow] =
                    (f16)acc_o[mi][nj][rr];
    __syncthreads();
#pragma unroll
    for (int it = 0; it < 8; ++it) {
        int c = it * 256 + t;
        int r = c >> 5, ck = c & 31;
        f16x8 v = *(const f16x8*)&Es[r * 264 + ck * 8];
        *(f16x8*)(WV + (size_t)(bb * SQ + m0 + r) * FH + h * 256 + ck * 8) = v;
    }
}

// ---------------------------------------------------------------------------
// out projection, split-K x8 over k = h*256+f. 128x128 tiles, grid (2,32,8).
// fp32 partials ALIASED onto dead qbuf/kbuf workspace (32 MB) -- no OOB.
// ---------------------------------------------------------------------------
__global__ __launch_bounds__(256) void out_mfma8(const f16* __restrict__ WVm,
                                                 const f16* __restrict__ WoT,
                                                 float* __restrict__ PP) {
    __shared__ f16 smem[16384];
    f16* As = smem;
    f16* Bs = smem + 8192;
    f32x4 acc[4][4] = {};
    const int row0 = blockIdx.y * 128, col0 = blockIdx.x * 128;
    const int kbeg = blockIdx.z * 256;
    gemm128_sw(WVm, FH, WoT, FH, kbeg, kbeg + 256, As, Bs, acc, row0, col0);

    float* P = PP + (size_t)blockIdx.z * SQ * 4 * FQ;
    const int lane = threadIdx.x & 63, w = threadIdx.x >> 6;
    const int wr = w >> 1, wc = w & 1;
    const int lrow = lane & 15, quad = lane >> 4;
#pragma unroll
    for (int i = 0; i < 4; ++i)
#pragma unroll
        for (int rr = 0; rr < 4; ++rr) {
            int gr = row0 + wr * 64 + i * 16 + quad * 4 + rr;
#pragma unroll
            for (int j = 0; j < 4; ++j) {
                int gc = col0 + wc * 64 + j * 16 + lrow;
                P[(size_t)gr * FQ + gc] = acc[i][j][rr];
            }
        }
}

__global__ __launch_bounds__(256) void reduce_relu8(const float* __restrict__ PP,
                                                    float* __restrict__ O) {
    int idx = (blockIdx.x * 256 + threadIdx.x) * 4;
    f32x4 s = *(const f32x4*)(PP + idx);
#pragma unroll
    for (int z = 1; z < 8; ++z)
        s += *(const f32x4*)(PP + (size_t)z * 1048576 + idx);
    f32x4 r = {fmaxf(s.x, 0.f), fmaxf(s.y, 0.f), fmaxf(s.z, 0.f), fmaxf(s.w, 0.f)};
    *(f32x4*)(O + idx) = r;
}

// ---------------------------------------------------------------------------
extern "C" void kernel_launch(void* const* d_in, const int* in_sizes, int n_in,
                              void* d_out, int out_size, void* d_ws, size_t ws_size,
                              hipStream_t stream) {
    const float* x  = (const float*)d_in[0];
    const float* Wq = (const float*)d_in[1];
    const float* Wk = (const float*)d_in[2];
    const float* Wv = (const float*)d_in[3];
    const float* Wo = (const float*)d_in[4];
    float* out = (float*)d_out;

    f16* ws = (f16*)d_ws;
    f16* xh    = ws;                       // 1,048,576
    f16* wqT   = xh    + 1048576;          // 524,288
    f16* wkT   = wqT   + 524288;
    f16* wvT   = wkT   + 524288;
    f16* woT   = wvT   + 524288;           // 524,288 (k permuted to h*256+f)
    f16* qbuf  = woT   + 524288;           // 8,388,608 (b,h,s,f)
    f16* kbuf  = qbuf  + 8388608;          // (b,h,s,f)
    f16* vbuf  = kbuf  + 8388608;          // (b,h,f,s)
    f16* wvbuf = vbuf  + 8388608;          // (b*s, h*256+f)
    // pp ALIASES qbuf+kbuf (dead after fused_attn): 8 x 1,048,576 fp32 = 32 MB.
    float* pp  = (float*)qbuf;

    dim3 blk(256);
    cvt_kernel<<<dim3(1024), blk, 0, stream>>>(x, xh);
    transpose_qkv<<<dim3(64, 8, 3), blk, 0, stream>>>(Wq, Wk, Wv, wqT, wkT, wvT);
    transpose_wo<<<dim3(8, 64), blk, 0, stream>>>(Wo, woT);

    proj_mfma<<<dim3(16, 32, 3), blk, 0, stream>>>(xh, wqT, wkT, wvT, qbuf, kbuf, vbuf);

    fused_attn<<<dim3(512), blk, 0, stream>>>(qbuf, kbuf, vbuf, wvbuf);

    out_mfma8<<<dim3(2, 32, 8), blk, 0, stream>>>(wvbuf, woT, pp);
    reduce_relu8<<<dim3(1024), blk, 0, stream>>>(pp, out);
}

// Round 10
// 198.099 us; speedup vs baseline: 1.2337x; 1.2337x over previous
//
#include <hip/hip_runtime.h>
#include <math.h>

// Problem: B=4, S=1024, F=256, H=8, FH=2048. SCALE=16 (multiplies logits).
#define SQ 1024
#define FQ 256
#define FH 2048

typedef _Float16 f16;
typedef f16  f16x8 __attribute__((ext_vector_type(8)));
typedef float f32x4 __attribute__((ext_vector_type(4)));

// Async global->LDS, 16 B/lane. LDS dest = wave-uniform base + lane*16.
// Crucially: an intrinsic with side effects -- the compiler cannot sink it
// past barriers the way it sinks plain register loads (v5/v6 failure mode).
#define GLOAD_LDS16(gp, lp) \
    __builtin_amdgcn_global_load_lds((const __attribute__((address_space(1))) void*)(gp), \
                                     (__attribute__((address_space(3))) void*)(lp), 16, 0, 0)

// ---------------------------------------------------------------------------
// prep kernel: z=0..2 transpose Wq/Wk/Wv (256x2048 fp32 -> 2048x256 f16);
// z=3 transpose Wo with k permuted to h*256+f; z=4 cvt x fp32->f16.
// grid (64, 8, 5), block 256.
// ---------------------------------------------------------------------------
__global__ __launch_bounds__(256) void prep_kernel(const float* __restrict__ x,
                                                   const float* __restrict__ Wq,
                                                   const float* __restrict__ Wk,
                                                   const float* __restrict__ Wv,
                                                   const float* __restrict__ Wo,
                                                   f16* __restrict__ xh,
                                                   f16* __restrict__ wqT,
                                                   f16* __restrict__ wkT,
                                                   f16* __restrict__ wvT,
                                                   f16* __restrict__ woT) {
    const int z = blockIdx.z;
    if (z == 4) {                        // cvt: 512 blocks x 256 thr x 8 elems
        int id = (int)(blockIdx.x * 8 + blockIdx.y);
        int idx = (id * 256 + (int)threadIdx.x) * 8;
        float4 a = *(const float4*)(x + idx);
        float4 b = *(const float4*)(x + idx + 4);
        f16x8 v = {(f16)a.x, (f16)a.y, (f16)a.z, (f16)a.w,
                   (f16)b.x, (f16)b.y, (f16)b.z, (f16)b.w};
        *(f16x8*)(xh + idx) = v;
        return;
    }
    __shared__ f16 T[32][33];
    const int tx = threadIdx.x & 31, ty = threadIdx.x >> 5;
    if (z < 3) {                         // qkv transpose
        const float* W = z == 0 ? Wq : (z == 1 ? Wk : Wv);
        f16* WT        = z == 0 ? wqT : (z == 1 ? wkT : wvT);
        const int n0 = blockIdx.x * 32, k0 = blockIdx.y * 32;
#pragma unroll
        for (int i = 0; i < 4; ++i)
            T[ty + i * 8][tx] = (f16)W[(size_t)(k0 + ty + i * 8) * FH + n0 + tx];
        __syncthreads();
#pragma unroll
        for (int i = 0; i < 4; ++i)
            WT[(size_t)(n0 + ty + i * 8) * FQ + k0 + tx] = T[tx][ty + i * 8];
    } else {                             // wo transpose, k permuted to h*256+f
        const int n0 = (blockIdx.x >> 3) * 32;
        const int yy = (blockIdx.x & 7) * 8 + blockIdx.y;   // 0..63
        const int ft = yy >> 3, h = yy & 7;
#pragma unroll
        for (int i = 0; i < 4; ++i) {
            int fl = ty + i * 8;
            T[fl][tx] = (f16)Wo[(size_t)((ft * 32 + fl) * 8 + h) * FQ + n0 + tx];
        }
        __syncthreads();
#pragma unroll
        for (int i = 0; i < 4; ++i)
            woT[(size_t)(n0 + ty + i * 8) * FH + h * 256 + ft * 32 + tx] = T[tx][ty + i * 8];
    }
}

// ---------------------------------------------------------------------------
// Swizzled staging, LDS row stride 64 f16 (BK=64 GEMM tiles).
// ---------------------------------------------------------------------------
__device__ __forceinline__ void stage_sw64(const f16* __restrict__ G, int ldg,
                                           int row0, int c0, f16* S,
                                           int nrows, int w, int lane) {
    const int rsub = lane >> 3;           // 0..7
    const int g    = (lane & 7) ^ (rsub & 7);
#pragma unroll
    for (int rI = w; rI < (nrows >> 3); rI += 4) {
        GLOAD_LDS16(G + (size_t)(row0 + rI * 8 + rsub) * ldg + c0 + g * 8,
                    S + rI * 512);
    }
}

// ---------------------------------------------------------------------------
// 128x128 MFMA tile, BK=64 swizzled staging. 4 waves 2x2 of 64x64.
// ---------------------------------------------------------------------------
__device__ __forceinline__ void gemm128_sw(const f16* __restrict__ A, int lda,
                                           const f16* __restrict__ Bt, int ldb,
                                           int kbeg, int kend, f16* As, f16* Bs,
                                           f32x4 acc[4][4], int row0, int col0) {
    const int t = threadIdx.x, lane = t & 63, w = t >> 6;
    const int wr = w >> 1, wc = w & 1;
    const int lrow = lane & 15, quad = lane >> 4;
    for (int k0 = kbeg; k0 < kend; k0 += 64) {
        __syncthreads();
        stage_sw64(A, lda, row0, k0, As, 128, w, lane);
        stage_sw64(Bt, ldb, col0, k0, Bs, 128, w, lane);
        __syncthreads();
#pragma unroll
        for (int kk = 0; kk < 2; ++kk) {
            f16x8 af[4], bf[4];
#pragma unroll
            for (int i = 0; i < 4; ++i) {
                int r = wr * 64 + i * 16 + lrow;
                af[i] = *(const f16x8*)&As[r * 64 + (((kk * 4 + quad) ^ (r & 7)) << 3)];
            }
#pragma unroll
            for (int j = 0; j < 4; ++j) {
                int r = wc * 64 + j * 16 + lrow;
                bf[j] = *(const f16x8*)&Bs[r * 64 + (((kk * 4 + quad) ^ (r & 7)) << 3)];
            }
#pragma unroll
            for (int i = 0; i < 4; ++i)
#pragma unroll
                for (int j = 0; j < 4; ++j)
                    acc[i][j] = __builtin_amdgcn_mfma_f32_16x16x32_f16(af[i], bf[j], acc[i][j], 0, 0, 0);
        }
    }
}

// ---------------------------------------------------------------------------
// Merged QKV projection with coalesced LDS-roundtrip epilogue.
// z=0 Q -> (b,h,s,f); z=1 K -> (b,h,s,f); z=2 V -> (b,h,f,s).
// ---------------------------------------------------------------------------
__global__ __launch_bounds__(256) void proj_mfma(const f16* __restrict__ xh,
                                                 const f16* __restrict__ wqT,
                                                 const f16* __restrict__ wkT,
                                                 const f16* __restrict__ wvT,
                                                 f16* __restrict__ qb,
                                                 f16* __restrict__ kb,
                                                 f16* __restrict__ vb) {
    const int z = blockIdx.z;
    const f16* WT = z == 0 ? wqT : (z == 1 ? wkT : wvT);
    f16* O        = z == 0 ? qb  : (z == 1 ? kb  : vb);
    __shared__ f16 smem[17408];          // As|Bs (16384) ; Es (17408) alias
    f16* As = smem;
    f16* Bs = smem + 8192;
    f32x4 acc[4][4] = {};
    const int row0 = blockIdx.y * 128, col0 = blockIdx.x * 128;
    gemm128_sw(xh, FQ, WT, FQ, 0, FQ, As, Bs, acc, row0, col0);

    __syncthreads();                     // As/Bs dead -> reuse as Es
    f16* Es = smem;                      // ld 136
    const int lane = threadIdx.x & 63, w = threadIdx.x >> 6;
    const int wr = w >> 1, wc = w & 1;
    const int lrow = lane & 15, quad = lane >> 4;
    if (z != 2) {
#pragma unroll
        for (int i = 0; i < 4; ++i)
#pragma unroll
            for (int rr = 0; rr < 4; ++rr) {
                int rl = 64 * wr + 16 * i + 4 * quad + rr;
#pragma unroll
                for (int j = 0; j < 4; ++j) {
                    int cc = 64 * wc + 16 * j + lrow;
                    Es[rl * 136 + (cc & 7) * 16 + (cc >> 3)] = (f16)acc[i][j][rr];
                }
            }
        __syncthreads();
        const int f0 = col0 >> 3;
#pragma unroll
        for (int it = 0; it < 4; ++it) {
            int c = it * 256 + threadIdx.x;
            int row = c >> 3, hh = c & 7;
            int gr = row0 + row, bbb = gr >> 10, s = gr & 1023;
            f16x8 v0 = *(const f16x8*)&Es[row * 136 + hh * 16];
            f16x8 v1 = *(const f16x8*)&Es[row * 136 + hh * 16 + 8];
            f16* dst = O + ((size_t)(bbb * 8 + hh) * SQ + s) * FQ + f0;
            *(f16x8*)dst = v0;
            *(f16x8*)(dst + 8) = v1;
        }
    } else {
#pragma unroll
        for (int i = 0; i < 4; ++i)
#pragma unroll
            for (int rr = 0; rr < 4; ++rr) {
                int rl = 64 * wr + 16 * i + 4 * quad + rr;
#pragma unroll
                for (int j = 0; j < 4; ++j) {
                    int cc = 64 * wc + 16 * j + lrow;
                    Es[cc * 136 + rl] = (f16)acc[i][j][rr];
                }
            }
        __syncthreads();
        const int bbb = row0 >> 10, s0 = row0 & 1023;
#pragma unroll
        for (int it = 0; it < 8; ++it) {
            int c = it * 256 + threadIdx.x;
            int cc = c >> 4, sc = c & 15;
            int hh = cc & 7, f = (col0 >> 3) + (cc >> 3);
            f16x8 v = *(const f16x8*)&Es[cc * 136 + sc * 8];
            *(f16x8*)(O + ((size_t)(bbb * 8 + hh) * FQ + f) * SQ + s0 + sc * 8) = v;
        }
    }
}

// ---------------------------------------------------------------------------
// Fused attention v7 — pinned-early-issue pipeline. 64 Q-rows per block,
// j-tile = 32 (32 iters), waves 2x2 (wr = 32-row half, wc = 16-col half /
// 128-f half).
//  - Q in registers (qf, loaded once).
//  - K tile (32x256) double-buffered in LDS via global_load_lds: K(jt+1)
//    issued at top of jt, drained at MID barrier (~400 cyc cover), used
//    next iteration. V tile (256x32) single-buffered, issued at top,
//    drained at mid, used in PV. Every vmcnt(0) inside __syncthreads now
//    waits on loads >=400 cycles old -> near-free drains. global_load_lds
//    cannot be sunk by the compiler (side-effecting intrinsic) -- this is
//    what v5/v6's register prefetch lacked.
//  - Source-address XOR swizzle keeps all LDS frag reads conflict-free.
// LDS: KB 2x16K + Vb 16K + Ps 4352 = 53504 B. VGPR ~180 -> 2 blocks/CU.
// ---------------------------------------------------------------------------
__global__ __launch_bounds__(256) void fused_attn(const f16* __restrict__ Qb,
                                                  const f16* __restrict__ Kb,
                                                  const f16* __restrict__ Vt,
                                                  f16* __restrict__ WV) {
    __shared__ f16 smem[26752];          // KB0 8192 | KB1 8192 | Vb 8192 | Ps 2176
    f16* KB0 = smem;                     // 32 x 256
    f16* KB1 = smem + 8192;
    f16* Vb  = smem + 16384;             // 256 x 32
    f16* Ps  = smem + 24576;             // 64 x 34
    const int t = threadIdx.x, lane = t & 63, w = t >> 6;
    const int wr = w >> 1, wc = w & 1;
    const int lrow = lane & 15, quad = lane >> 4;
    // XCD swizzle: 4 consecutive heads per XCD -> Q/K/V L2-resident per XCD.
    const int n = blockIdx.x;
    const int xcd = n & 7, rest = n >> 3;
    const int bh = xcd * 4 + (rest & 3);
    const int strip = rest >> 2;                 // 0..15
    const int m0 = strip * 64;
    const int bb = bh >> 3, h = bh & 7;
    const f16* Qg = Qb + (size_t)bh * SQ * FQ;   // (s,f)
    const f16* Kg = Kb + (size_t)bh * SQ * FQ;   // (s,f)
    const f16* Vg = Vt + (size_t)bh * FQ * SQ;   // (f,s)

    // Q rows [m0+32wr, +32) as A-fragments in registers (64 VGPR, loaded once).
    f16x8 qf[2][8];
#pragma unroll
    for (int mi = 0; mi < 2; ++mi)
#pragma unroll
        for (int ks = 0; ks < 8; ++ks)
            qf[mi][ks] = *(const f16x8*)(Qg + (size_t)(m0 + 32 * wr + 16 * mi + lrow) * FQ
                                             + ks * 32 + quad * 8);

    // K staging geometry: 16 insts (4/wave), each 2 rows x 32 granules.
    // LDS[r][p] holds source granule p^(r&7); read logical g at p=g^(r&7).
    const int krs = lane >> 5;                   // 0..1 row-within-inst
    const int kgp = lane & 31;                   // LDS slot granule
    // V staging geometry: 16 insts (4/wave), each 16 rows x 4 granules.
    const int vrs = lane >> 2;                   // 0..15 row-within-inst
    const int vgp = lane & 3;                    // LDS slot granule

    // Prologue: issue K(0) -> KB0.
#pragma unroll
    for (int i = 0; i < 4; ++i) {
        int rI = w + i * 4;
        int r = rI * 2 + krs;
        GLOAD_LDS16(Kg + (size_t)r * FQ + ((kgp ^ (r & 7)) << 3), KB0 + rI * 512);
    }

    f32x4 acc_o[2][8] = {};   // rows 32wr+16mi(+4quad+rr), f = 128wc+16nj+lrow

    for (int jt = 0; jt < 32; ++jt) {
        const int j0 = jt * 32;
        f16* KBc = (jt & 1) ? KB1 : KB0;
        f16* KBn = (jt & 1) ? KB0 : KB1;
        __syncthreads();                 // K(jt) old (drained at prev mid); WAR Vb/Ps
        // ---- issue V(jt) and K(jt+1) (drained at mid, ~400 cyc away) ----
#pragma unroll
        for (int i = 0; i < 4; ++i) {
            int rI = w + i * 4;
            int f = rI * 16 + vrs;
            GLOAD_LDS16(Vg + (size_t)f * SQ + j0 + ((vgp ^ (f & 3)) << 3), Vb + rI * 512);
        }
        if (jt < 31) {
#pragma unroll
            for (int i = 0; i < 4; ++i) {
                int rI = w + i * 4;
                int r = rI * 2 + krs;
                GLOAD_LDS16(Kg + (size_t)(j0 + 32 + r) * FQ + ((kgp ^ (r & 7)) << 3),
                            KBn + rI * 512);
            }
        }
        // ---- QK^T from KBc: S rows 32wr..+32, cols 16wc..+16, K-dim 256 ----
        f32x4 acc_s[2] = {};
#pragma unroll
        for (int ks = 0; ks < 8; ++ks) {
            int r = 16 * wc + lrow;
            f16x8 bf = *(const f16x8*)&KBc[r * 256 + (((ks * 4 + quad) ^ (r & 7)) << 3)];
#pragma unroll
            for (int mi = 0; mi < 2; ++mi)
                acc_s[mi] = __builtin_amdgcn_mfma_f32_16x16x32_f16(qf[mi][ks], bf, acc_s[mi], 0, 0, 0);
        }
        // ---- sigmoid -> Ps (ld 34; C-frag col=lane&15, row=4quad+rr) ----
#pragma unroll
        for (int mi = 0; mi < 2; ++mi)
#pragma unroll
            for (int rr = 0; rr < 4; ++rr)
                Ps[(32 * wr + 16 * mi + 4 * quad + rr) * 34 + 16 * wc + lrow] =
                    (f16)(1.0f / (1.0f + __expf(-16.0f * acc_s[mi][rr])));
        __syncthreads();                 // V(jt)+K(jt+1) drained (old); Ps visible
        // ---- PV: WV(64x256) += P(64x32) @ V^T; one K=32 MFMA pass ----
        f16x8 ap[2];
#pragma unroll
        for (int mi = 0; mi < 2; ++mi)
            ap[mi] = *(const f16x8*)&Ps[(32 * wr + 16 * mi + lrow) * 34 + quad * 8];
#pragma unroll
        for (int nj = 0; nj < 8; ++nj) {
            int f = 128 * wc + 16 * nj + lrow;
            f16x8 bv = *(const f16x8*)&Vb[f * 32 + ((quad ^ (f & 3)) << 3)];
#pragma unroll
            for (int mi = 0; mi < 2; ++mi)
                acc_o[mi][nj] = __builtin_amdgcn_mfma_f32_16x16x32_f16(
                    ap[mi], bv, acc_o[mi][nj], 0, 0, 0);
        }
    }
    // ---- epilogue: LDS roundtrip -> 512 B contiguous rows ----
    __syncthreads();                             // smem dead
    f16* Es = smem;                              // 64 x 264 = 33792 B
#pragma unroll
    for (int mi = 0; mi < 2; ++mi)
#pragma unroll
        for (int nj = 0; nj < 8; ++nj)
#pragma unroll
            for (int rr = 0; rr < 4; ++rr)
                Es[(32 * wr + 16 * mi + 4 * quad + rr) * 264 + 128 * wc + 16 * nj + lrow] =
                    (f16)acc_o[mi][nj][rr];
    __syncthreads();
#pragma unroll
    for (int it = 0; it < 8; ++it) {
        int c = it * 256 + t;
        int r = c >> 5, ck = c & 31;
        f16x8 v = *(const f16x8*)&Es[r * 264 + ck * 8];
        *(f16x8*)(WV + (size_t)(bb * SQ + m0 + r) * FH + h * 256 + ck * 8) = v;
    }
}

// ---------------------------------------------------------------------------
// out projection, split-K x8 over k = h*256+f. 128x128 tiles, grid (2,32,8).
// fp32 partials ALIASED onto dead qbuf/kbuf workspace (32 MB) -- no OOB.
// ---------------------------------------------------------------------------
__global__ __launch_bounds__(256) void out_mfma8(const f16* __restrict__ WVm,
                                                 const f16* __restrict__ WoT,
                                                 float* __restrict__ PP) {
    __shared__ f16 smem[16384];
    f16* As = smem;
    f16* Bs = smem + 8192;
    f32x4 acc[4][4] = {};
    const int row0 = blockIdx.y * 128, col0 = blockIdx.x * 128;
    const int kbeg = blockIdx.z * 256;
    gemm128_sw(WVm, FH, WoT, FH, kbeg, kbeg + 256, As, Bs, acc, row0, col0);

    float* P = PP + (size_t)blockIdx.z * SQ * 4 * FQ;
    const int lane = threadIdx.x & 63, w = threadIdx.x >> 6;
    const int wr = w >> 1, wc = w & 1;
    const int lrow = lane & 15, quad = lane >> 4;
#pragma unroll
    for (int i = 0; i < 4; ++i)
#pragma unroll
        for (int rr = 0; rr < 4; ++rr) {
            int gr = row0 + wr * 64 + i * 16 + quad * 4 + rr;
#pragma unroll
            for (int j = 0; j < 4; ++j) {
                int gc = col0 + wc * 64 + j * 16 + lrow;
                P[(size_t)gr * FQ + gc] = acc[i][j][rr];
            }
        }
}

__global__ __launch_bounds__(256) void reduce_relu8(const float* __restrict__ PP,
                                                    float* __restrict__ O) {
    int idx = (blockIdx.x * 256 + threadIdx.x) * 4;
    f32x4 s = *(const f32x4*)(PP + idx);
#pragma unroll
    for (int z = 1; z < 8; ++z)
        s += *(const f32x4*)(PP + (size_t)z * 1048576 + idx);
    f32x4 r = {fmaxf(s.x, 0.f), fmaxf(s.y, 0.f), fmaxf(s.z, 0.f), fmaxf(s.w, 0.f)};
    *(f32x4*)(O + idx) = r;
}

// ---------------------------------------------------------------------------
extern "C" void kernel_launch(void* const* d_in, const int* in_sizes, int n_in,
                              void* d_out, int out_size, void* d_ws, size_t ws_size,
                              hipStream_t stream) {
    const float* x  = (const float*)d_in[0];
    const float* Wq = (const float*)d_in[1];
    const float* Wk = (const float*)d_in[2];
    const float* Wv = (const float*)d_in[3];
    const float* Wo = (const float*)d_in[4];
    float* out = (float*)d_out;

    f16* ws = (f16*)d_ws;
    f16* xh    = ws;                       // 1,048,576
    f16* wqT   = xh    + 1048576;          // 524,288
    f16* wkT   = wqT   + 524288;
    f16* wvT   = wkT   + 524288;
    f16* woT   = wvT   + 524288;           // 524,288 (k permuted to h*256+f)
    f16* qbuf  = woT   + 524288;           // 8,388,608 (b,h,s,f)
    f16* kbuf  = qbuf  + 8388608;          // (b,h,s,f)
    f16* vbuf  = kbuf  + 8388608;          // (b,h,f,s)
    f16* wvbuf = vbuf  + 8388608;          // (b*s, h*256+f)
    // pp ALIASES qbuf+kbuf (dead after fused_attn): 8 x 1,048,576 fp32 = 32 MB.
    float* pp  = (float*)qbuf;

    dim3 blk(256);
    prep_kernel<<<dim3(64, 8, 5), blk, 0, stream>>>(x, Wq, Wk, Wv, Wo,
                                                    xh, wqT, wkT, wvT, woT);

    proj_mfma<<<dim3(16, 32, 3), blk, 0, stream>>>(xh, wqT, wkT, wvT, qbuf, kbuf, vbuf);

    fused_attn<<<dim3(512), blk, 0, stream>>>(qbuf, kbuf, vbuf, wvbuf);

    out_mfma8<<<dim3(2, 32, 8), blk, 0, stream>>>(wvbuf, woT, pp);
    reduce_relu8<<<dim3(1024), blk, 0, stream>>>(pp, out);
}

// Round 12
// 184.375 us; speedup vs baseline: 1.3255x; 1.0744x over previous
//
#include <hip/hip_runtime.h>
#include <math.h>

// Problem: B=4, S=1024, F=256, H=8, FH=2048. SCALE=16 (multiplies logits).
#define SQ 1024
#define FQ 256
#define FH 2048

typedef _Float16 f16;
typedef f16  f16x8 __attribute__((ext_vector_type(8)));
typedef float f32x4 __attribute__((ext_vector_type(4)));

// Async global->LDS, 16 B/lane. LDS dest = wave-uniform base + lane*16.
// Side-effecting intrinsic: cannot be sunk past barriers by the compiler.
#define GLOAD_LDS16(gp, lp) \
    __builtin_amdgcn_global_load_lds((const __attribute__((address_space(1))) void*)(gp), \
                                     (__attribute__((address_space(3))) void*)(lp), 16, 0, 0)

// sigmoid(16*s) = 1/(1+e^{-16s}) = rcp(1+exp2(-16*log2(e)*s)); v_rcp+v_exp,
// no IEEE divide sequence (we don't compile with -ffast-math).
#define SIG16(s) __builtin_amdgcn_rcpf(1.0f + __builtin_amdgcn_exp2f(-23.083120654223414f * (s)))

// ---------------------------------------------------------------------------
// prep kernel: z=0..2 transpose Wq/Wk/Wv (256x2048 fp32 -> 2048x256 f16);
// z=3 transpose Wo with k permuted to h*256+f; z=4 cvt x fp32->f16.
// ---------------------------------------------------------------------------
__global__ __launch_bounds__(256) void prep_kernel(const float* __restrict__ x,
                                                   const float* __restrict__ Wq,
                                                   const float* __restrict__ Wk,
                                                   const float* __restrict__ Wv,
                                                   const float* __restrict__ Wo,
                                                   f16* __restrict__ xh,
                                                   f16* __restrict__ wqT,
                                                   f16* __restrict__ wkT,
                                                   f16* __restrict__ wvT,
                                                   f16* __restrict__ woT) {
    const int z = blockIdx.z;
    if (z == 4) {
        int id = (int)(blockIdx.x * 8 + blockIdx.y);
        int idx = (id * 256 + (int)threadIdx.x) * 8;
        float4 a = *(const float4*)(x + idx);
        float4 b = *(const float4*)(x + idx + 4);
        f16x8 v = {(f16)a.x, (f16)a.y, (f16)a.z, (f16)a.w,
                   (f16)b.x, (f16)b.y, (f16)b.z, (f16)b.w};
        *(f16x8*)(xh + idx) = v;
        return;
    }
    __shared__ f16 T[32][33];
    const int tx = threadIdx.x & 31, ty = threadIdx.x >> 5;
    if (z < 3) {
        const float* W = z == 0 ? Wq : (z == 1 ? Wk : Wv);
        f16* WT        = z == 0 ? wqT : (z == 1 ? wkT : wvT);
        const int n0 = blockIdx.x * 32, k0 = blockIdx.y * 32;
#pragma unroll
        for (int i = 0; i < 4; ++i)
            T[ty + i * 8][tx] = (f16)W[(size_t)(k0 + ty + i * 8) * FH + n0 + tx];
        __syncthreads();
#pragma unroll
        for (int i = 0; i < 4; ++i)
            WT[(size_t)(n0 + ty + i * 8) * FQ + k0 + tx] = T[tx][ty + i * 8];
    } else {
        const int n0 = (blockIdx.x >> 3) * 32;
        const int yy = (blockIdx.x & 7) * 8 + blockIdx.y;   // 0..63
        const int ft = yy >> 3, h = yy & 7;
#pragma unroll
        for (int i = 0; i < 4; ++i) {
            int fl = ty + i * 8;
            T[fl][tx] = (f16)Wo[(size_t)((ft * 32 + fl) * 8 + h) * FQ + n0 + tx];
        }
        __syncthreads();
#pragma unroll
        for (int i = 0; i < 4; ++i)
            woT[(size_t)(n0 + ty + i * 8) * FH + h * 256 + ft * 32 + tx] = T[tx][ty + i * 8];
    }
}

// ---------------------------------------------------------------------------
// Swizzled staging, LDS row stride 64 f16 (BK=64 GEMM tiles).
// ---------------------------------------------------------------------------
__device__ __forceinline__ void stage_sw64(const f16* __restrict__ G, int ldg,
                                           int row0, int c0, f16* S,
                                           int nrows, int w, int lane) {
    const int rsub = lane >> 3;           // 0..7
    const int g    = (lane & 7) ^ (rsub & 7);
#pragma unroll
    for (int rI = w; rI < (nrows >> 3); rI += 4) {
        GLOAD_LDS16(G + (size_t)(row0 + rI * 8 + rsub) * ldg + c0 + g * 8,
                    S + rI * 512);
    }
}

// ---------------------------------------------------------------------------
// 128x128 MFMA tile, BK=64 swizzled staging. 4 waves 2x2 of 64x64.
// ---------------------------------------------------------------------------
__device__ __forceinline__ void gemm128_sw(const f16* __restrict__ A, int lda,
                                           const f16* __restrict__ Bt, int ldb,
                                           int kbeg, int kend, f16* As, f16* Bs,
                                           f32x4 acc[4][4], int row0, int col0) {
    const int t = threadIdx.x, lane = t & 63, w = t >> 6;
    const int wr = w >> 1, wc = w & 1;
    const int lrow = lane & 15, quad = lane >> 4;
    for (int k0 = kbeg; k0 < kend; k0 += 64) {
        __syncthreads();
        stage_sw64(A, lda, row0, k0, As, 128, w, lane);
        stage_sw64(Bt, ldb, col0, k0, Bs, 128, w, lane);
        __syncthreads();
#pragma unroll
        for (int kk = 0; kk < 2; ++kk) {
            f16x8 af[4], bf[4];
#pragma unroll
            for (int i = 0; i < 4; ++i) {
                int r = wr * 64 + i * 16 + lrow;
                af[i] = *(const f16x8*)&As[r * 64 + (((kk * 4 + quad) ^ (r & 7)) << 3)];
            }
#pragma unroll
            for (int j = 0; j < 4; ++j) {
                int r = wc * 64 + j * 16 + lrow;
                bf[j] = *(const f16x8*)&Bs[r * 64 + (((kk * 4 + quad) ^ (r & 7)) << 3)];
            }
#pragma unroll
            for (int i = 0; i < 4; ++i)
#pragma unroll
                for (int j = 0; j < 4; ++j)
                    acc[i][j] = __builtin_amdgcn_mfma_f32_16x16x32_f16(af[i], bf[j], acc[i][j], 0, 0, 0);
        }
    }
}

// ---------------------------------------------------------------------------
// Merged QKV projection with coalesced LDS-roundtrip epilogue.
// z=0 Q -> (b,h,s,f); z=1 K -> (b,h,s,f); z=2 V -> (b,h,f,s).
// ---------------------------------------------------------------------------
__global__ __launch_bounds__(256) void proj_mfma(const f16* __restrict__ xh,
                                                 const f16* __restrict__ wqT,
                                                 const f16* __restrict__ wkT,
                                                 const f16* __restrict__ wvT,
                                                 f16* __restrict__ qb,
                                                 f16* __restrict__ kb,
                                                 f16* __restrict__ vb) {
    const int z = blockIdx.z;
    const f16* WT = z == 0 ? wqT : (z == 1 ? wkT : wvT);
    f16* O        = z == 0 ? qb  : (z == 1 ? kb  : vb);
    __shared__ f16 smem[17408];          // As|Bs (16384) ; Es (17408) alias
    f16* As = smem;
    f16* Bs = smem + 8192;
    f32x4 acc[4][4] = {};
    const int row0 = blockIdx.y * 128, col0 = blockIdx.x * 128;
    gemm128_sw(xh, FQ, WT, FQ, 0, FQ, As, Bs, acc, row0, col0);

    __syncthreads();                     // As/Bs dead -> reuse as Es
    f16* Es = smem;                      // ld 136
    const int lane = threadIdx.x & 63, w = threadIdx.x >> 6;
    const int wr = w >> 1, wc = w & 1;
    const int lrow = lane & 15, quad = lane >> 4;
    if (z != 2) {
#pragma unroll
        for (int i = 0; i < 4; ++i)
#pragma unroll
            for (int rr = 0; rr < 4; ++rr) {
                int rl = 64 * wr + 16 * i + 4 * quad + rr;
#pragma unroll
                for (int j = 0; j < 4; ++j) {
                    int cc = 64 * wc + 16 * j + lrow;
                    Es[rl * 136 + (cc & 7) * 16 + (cc >> 3)] = (f16)acc[i][j][rr];
                }
            }
        __syncthreads();
        const int f0 = col0 >> 3;
#pragma unroll
        for (int it = 0; it < 4; ++it) {
            int c = it * 256 + threadIdx.x;
            int row = c >> 3, hh = c & 7;
            int gr = row0 + row, bbb = gr >> 10, s = gr & 1023;
            f16x8 v0 = *(const f16x8*)&Es[row * 136 + hh * 16];
            f16x8 v1 = *(const f16x8*)&Es[row * 136 + hh * 16 + 8];
            f16* dst = O + ((size_t)(bbb * 8 + hh) * SQ + s) * FQ + f0;
            *(f16x8*)dst = v0;
            *(f16x8*)(dst + 8) = v1;
        }
    } else {
#pragma unroll
        for (int i = 0; i < 4; ++i)
#pragma unroll
            for (int rr = 0; rr < 4; ++rr) {
                int rl = 64 * wr + 16 * i + 4 * quad + rr;
#pragma unroll
                for (int j = 0; j < 4; ++j) {
                    int cc = 64 * wc + 16 * j + lrow;
                    Es[cc * 136 + rl] = (f16)acc[i][j][rr];
                }
            }
        __syncthreads();
        const int bbb = row0 >> 10, s0 = row0 & 1023;
#pragma unroll
        for (int it = 0; it < 8; ++it) {
            int c = it * 256 + threadIdx.x;
            int cc = c >> 4, sc = c & 15;
            int hh = cc & 7, f = (col0 >> 3) + (cc >> 3);
            f16x8 v = *(const f16x8*)&Es[cc * 136 + sc * 8];
            *(f16x8*)(O + ((size_t)(bbb * 8 + hh) * FQ + f) * SQ + s0 + sc * 8) = v;
        }
    }
}

// ---------------------------------------------------------------------------
// Fused attention v8b — one barrier/iter, wave-private P. (v8 with the
// LDS-pointer-array compile issue fixed via scalar ternaries.)
// Per block: 64 Q-rows of (b,h); wave w owns rows 16w..16w+16 (1x4 layout).
// j-tile = 32. Per iteration jt:
//   [__syncthreads]  <- drains K(jt),V(jt) (issued one FULL iteration ago)
//   issue K(jt+1), V(jt+1)   (global_load_lds, pinned)
//   QK: S(16x32) (16 MFMA) -> sigmoid (rcp/exp2)
//   -> wave-PRIVATE Ps (in-order LDS, NO barrier) -> A-frag read
//   PV: WV(16x256) += P(16x32) @ V^T (16 MFMA)
// LDS: KB 2x16K + VB 2x16K + Ps 4x1.25K = 70656 B -> 2 blocks/CU.
// ---------------------------------------------------------------------------
__global__ __launch_bounds__(256) void fused_attn(const f16* __restrict__ Qb,
                                                  const f16* __restrict__ Kb,
                                                  const f16* __restrict__ Vt,
                                                  f16* __restrict__ WV) {
    __shared__ f16 smem[35328];   // KB0 8192 | KB1 8192 | VB0 8192 | VB1 8192 | Ps 4x640
    const int t = threadIdx.x, lane = t & 63, w = t >> 6;
    const int lrow = lane & 15, quad = lane >> 4;
    f16* Pw = smem + 32768 + w * 640;            // wave-private 16 x 40
    // XCD swizzle: 4 consecutive heads per XCD -> Q/K/V L2-resident per XCD.
    const int n = blockIdx.x;
    const int xcd = n & 7, rest = n >> 3;
    const int bh = xcd * 4 + (rest & 3);
    const int strip = rest >> 2;                 // 0..15
    const int m0 = strip * 64;
    const int bb = bh >> 3, h = bh & 7;
    const f16* Qg = Qb + (size_t)bh * SQ * FQ;   // (s,f)
    const f16* Kg = Kb + (size_t)bh * SQ * FQ;   // (s,f)
    const f16* Vg = Vt + (size_t)bh * FQ * SQ;   // (f,s)

    // Q rows [m0+16w, +16) as A-fragments in registers (32 VGPR, loaded once).
    f16x8 qf[8];
#pragma unroll
    for (int ks = 0; ks < 8; ++ks)
        qf[ks] = *(const f16x8*)(Qg + (size_t)(m0 + 16 * w + lrow) * FQ + ks * 32 + quad * 8);

    // K staging geometry: 16 insts (4/wave), 2 rows x 32 granules each.
    // KB[r][p] holds source granule p^(r&7); read logical g at p = g^(r&7).
    const int krs = lane >> 5;                   // 0..1
    const int kgp = lane & 31;
    // V staging geometry: 16 insts (4/wave), 16 rows x 4 granules each.
    // VB[f][p] holds source granule p^((f>>1)&3); read at p = g^((f>>1)&3).
    const int vrs = lane >> 2;                   // 0..15
    const int vgp = lane & 3;

    // Prologue: issue K(0) -> KB0 and V(0) -> VB0.
#pragma unroll
    for (int i = 0; i < 4; ++i) {
        int rI = w + i * 4;
        int r = rI * 2 + krs;
        GLOAD_LDS16(Kg + (size_t)r * FQ + ((kgp ^ (r & 7)) << 3), smem + rI * 512);
    }
#pragma unroll
    for (int i = 0; i < 4; ++i) {
        int rI = w + i * 4;
        int f = rI * 16 + vrs;
        GLOAD_LDS16(Vg + (size_t)f * SQ + ((vgp ^ ((f >> 1) & 3)) << 3),
                    smem + 16384 + rI * 512);
    }

    f32x4 acc_o[16] = {};   // WV rows 16w+4quad+rr, f = 16nj+lrow

    for (int jt = 0; jt < 32; ++jt) {
        const int j0 = jt * 32;
        f16* KBc = (jt & 1) ? smem + 8192  : smem;
        f16* VBc = (jt & 1) ? smem + 24576 : smem + 16384;
        __syncthreads();                 // drains K(jt),V(jt): one full iter old
        // ---- issue K(jt+1), V(jt+1) into the other buffers ----
        if (jt < 31) {
            f16* KBn = (jt & 1) ? smem         : smem + 8192;
            f16* VBn = (jt & 1) ? smem + 16384 : smem + 24576;
#pragma unroll
            for (int i = 0; i < 4; ++i) {
                int rI = w + i * 4;
                int r = rI * 2 + krs;
                GLOAD_LDS16(Kg + (size_t)(j0 + 32 + r) * FQ + ((kgp ^ (r & 7)) << 3),
                            KBn + rI * 512);
            }
#pragma unroll
            for (int i = 0; i < 4; ++i) {
                int rI = w + i * 4;
                int f = rI * 16 + vrs;
                GLOAD_LDS16(Vg + (size_t)f * SQ + j0 + 32 + ((vgp ^ ((f >> 1) & 3)) << 3),
                            VBn + rI * 512);
            }
        }
        // ---- QK^T: S(16x32) rows 16w..+16, cols j0..+32; K-dim 256 ----
        f32x4 acc_s[2] = {};
#pragma unroll
        for (int ks = 0; ks < 8; ++ks) {
#pragma unroll
            for (int nj = 0; nj < 2; ++nj) {
                int rk = 16 * nj + lrow;
                f16x8 bf = *(const f16x8*)&KBc[rk * 256 + (((ks * 4 + quad) ^ (rk & 7)) << 3)];
                acc_s[nj] = __builtin_amdgcn_mfma_f32_16x16x32_f16(qf[ks], bf, acc_s[nj], 0, 0, 0);
            }
        }
        // ---- sigmoid -> wave-private Ps (NO barrier: in-order own-wave LDS) ----
#pragma unroll
        for (int nj = 0; nj < 2; ++nj)
#pragma unroll
            for (int rr = 0; rr < 4; ++rr)
                Pw[(4 * quad + rr) * 40 + 16 * nj + lrow] = (f16)SIG16(acc_s[nj][rr]);
        // ---- P as A-frag; PV: WV(16x256) += P(16x32) @ V^T ----
        f16x8 ap = *(const f16x8*)&Pw[lrow * 40 + quad * 8];
#pragma unroll
        for (int nj = 0; nj < 16; ++nj) {
            int f = 16 * nj + lrow;
            f16x8 bv = *(const f16x8*)&VBc[f * 32 + ((quad ^ ((f >> 1) & 3)) << 3)];
            acc_o[nj] = __builtin_amdgcn_mfma_f32_16x16x32_f16(ap, bv, acc_o[nj], 0, 0, 0);
        }
    }
    // ---- epilogue: LDS roundtrip -> 512 B contiguous rows ----
    __syncthreads();                             // smem dead
    f16* Es = smem;                              // 64 x 264 = 33792 B
#pragma unroll
    for (int nj = 0; nj < 16; ++nj)
#pragma unroll
        for (int rr = 0; rr < 4; ++rr)
            Es[(16 * w + 4 * quad + rr) * 264 + 16 * nj + lrow] = (f16)acc_o[nj][rr];
    __syncthreads();
#pragma unroll
    for (int it = 0; it < 8; ++it) {
        int c = it * 256 + t;
        int r = c >> 5, ck = c & 31;
        f16x8 v = *(const f16x8*)&Es[r * 264 + ck * 8];
        *(f16x8*)(WV + (size_t)(bb * SQ + m0 + r) * FH + h * 256 + ck * 8) = v;
    }
}

// ---------------------------------------------------------------------------
// out projection, split-K x8 over k = h*256+f. 128x128 tiles, grid (2,32,8).
// fp32 partials ALIASED onto dead qbuf/kbuf workspace (32 MB) -- no OOB.
// ---------------------------------------------------------------------------
__global__ __launch_bounds__(256) void out_mfma8(const f16* __restrict__ WVm,
                                                 const f16* __restrict__ WoT,
                                                 float* __restrict__ PP) {
    __shared__ f16 smem[16384];
    f16* As = smem;
    f16* Bs = smem + 8192;
    f32x4 acc[4][4] = {};
    const int row0 = blockIdx.y * 128, col0 = blockIdx.x * 128;
    const int kbeg = blockIdx.z * 256;
    gemm128_sw(WVm, FH, WoT, FH, kbeg, kbeg + 256, As, Bs, acc, row0, col0);

    float* P = PP + (size_t)blockIdx.z * SQ * 4 * FQ;
    const int lane = threadIdx.x & 63, w = threadIdx.x >> 6;
    const int wr = w >> 1, wc = w & 1;
    const int lrow = lane & 15, quad = lane >> 4;
#pragma unroll
    for (int i = 0; i < 4; ++i)
#pragma unroll
        for (int rr = 0; rr < 4; ++rr) {
            int gr = row0 + wr * 64 + i * 16 + quad * 4 + rr;
#pragma unroll
            for (int j = 0; j < 4; ++j) {
                int gc = col0 + wc * 64 + j * 16 + lrow;
                P[(size_t)gr * FQ + gc] = acc[i][j][rr];
            }
        }
}

__global__ __launch_bounds__(256) void reduce_relu8(const float* __restrict__ PP,
                                                    float* __restrict__ O) {
    int idx = (blockIdx.x * 256 + threadIdx.x) * 4;
    f32x4 s = *(const f32x4*)(PP + idx);
#pragma unroll
    for (int z = 1; z < 8; ++z)
        s += *(const f32x4*)(PP + (size_t)z * 1048576 + idx);
    f32x4 r = {fmaxf(s.x, 0.f), fmaxf(s.y, 0.f), fmaxf(s.z, 0.f), fmaxf(s.w, 0.f)};
    *(f32x4*)(O + idx) = r;
}

// ---------------------------------------------------------------------------
extern "C" void kernel_launch(void* const* d_in, const int* in_sizes, int n_in,
                              void* d_out, int out_size, void* d_ws, size_t ws_size,
                              hipStream_t stream) {
    const float* x  = (const float*)d_in[0];
    const float* Wq = (const float*)d_in[1];
    const float* Wk = (const float*)d_in[2];
    const float* Wv = (const float*)d_in[3];
    const float* Wo = (const float*)d_in[4];
    float* out = (float*)d_out;

    f16* ws = (f16*)d_ws;
    f16* xh    = ws;                       // 1,048,576
    f16* wqT   = xh    + 1048576;          // 524,288
    f16* wkT   = wqT   + 524288;
    f16* wvT   = wkT   + 524288;
    f16* woT   = wvT   + 524288;           // 524,288 (k permuted to h*256+f)
    f16* qbuf  = woT   + 524288;           // 8,388,608 (b,h,s,f)
    f16* kbuf  = qbuf  + 8388608;          // (b,h,s,f)
    f16* vbuf  = kbuf  + 8388608;          // (b,h,f,s)
    f16* wvbuf = vbuf  + 8388608;          // (b*s, h*256+f)
    // pp ALIASES qbuf+kbuf (dead after fused_attn): 8 x 1,048,576 fp32 = 32 MB.
    float* pp  = (float*)qbuf;

    dim3 blk(256);
    prep_kernel<<<dim3(64, 8, 5), blk, 0, stream>>>(x, Wq, Wk, Wv, Wo,
                                                    xh, wqT, wkT, wvT, woT);

    proj_mfma<<<dim3(16, 32, 3), blk, 0, stream>>>(xh, wqT, wkT, wvT, qbuf, kbuf, vbuf);

    fused_attn<<<dim3(512), blk, 0, stream>>>(qbuf, kbuf, vbuf, wvbuf);

    out_mfma8<<<dim3(2, 32, 8), blk, 0, stream>>>(wvbuf, woT, pp);
    reduce_relu8<<<dim3(1024), blk, 0, stream>>>(pp, out);
}

// Round 13
// 182.629 us; speedup vs baseline: 1.3382x; 1.0096x over previous
//
#include <hip/hip_runtime.h>
#include <math.h>

// Problem: B=4, S=1024, F=256, H=8, FH=2048. SCALE=16 (multiplies logits).
#define SQ 1024
#define FQ 256
#define FH 2048

typedef _Float16 f16;
typedef f16  f16x8 __attribute__((ext_vector_type(8)));
typedef float f32x4 __attribute__((ext_vector_type(4)));

// Async global->LDS, 16 B/lane. LDS dest = wave-uniform base + lane*16.
// Side-effecting intrinsic: cannot be sunk past barriers by the compiler.
#define GLOAD_LDS16(gp, lp) \
    __builtin_amdgcn_global_load_lds((const __attribute__((address_space(1))) void*)(gp), \
                                     (__attribute__((address_space(3))) void*)(lp), 16, 0, 0)

// sigmoid(16*s) = rcp(1+exp2(-16*log2(e)*s)); v_rcp+v_exp, no IEEE divide.
#define SIG16(s) __builtin_amdgcn_rcpf(1.0f + __builtin_amdgcn_exp2f(-23.083120654223414f * (s)))

// ---------------------------------------------------------------------------
// prep kernel: z=0..2 transpose Wq/Wk/Wv (256x2048 fp32 -> 2048x256 f16);
// z=3 transpose Wo with k permuted to h*256+f; z=4 cvt x fp32->f16.
// ---------------------------------------------------------------------------
__global__ __launch_bounds__(256) void prep_kernel(const float* __restrict__ x,
                                                   const float* __restrict__ Wq,
                                                   const float* __restrict__ Wk,
                                                   const float* __restrict__ Wv,
                                                   const float* __restrict__ Wo,
                                                   f16* __restrict__ xh,
                                                   f16* __restrict__ wqT,
                                                   f16* __restrict__ wkT,
                                                   f16* __restrict__ wvT,
                                                   f16* __restrict__ woT) {
    const int z = blockIdx.z;
    if (z == 4) {
        int id = (int)(blockIdx.x * 8 + blockIdx.y);
        int idx = (id * 256 + (int)threadIdx.x) * 8;
        float4 a = *(const float4*)(x + idx);
        float4 b = *(const float4*)(x + idx + 4);
        f16x8 v = {(f16)a.x, (f16)a.y, (f16)a.z, (f16)a.w,
                   (f16)b.x, (f16)b.y, (f16)b.z, (f16)b.w};
        *(f16x8*)(xh + idx) = v;
        return;
    }
    __shared__ f16 T[32][33];
    const int tx = threadIdx.x & 31, ty = threadIdx.x >> 5;
    if (z < 3) {
        const float* W = z == 0 ? Wq : (z == 1 ? Wk : Wv);
        f16* WT        = z == 0 ? wqT : (z == 1 ? wkT : wvT);
        const int n0 = blockIdx.x * 32, k0 = blockIdx.y * 32;
#pragma unroll
        for (int i = 0; i < 4; ++i)
            T[ty + i * 8][tx] = (f16)W[(size_t)(k0 + ty + i * 8) * FH + n0 + tx];
        __syncthreads();
#pragma unroll
        for (int i = 0; i < 4; ++i)
            WT[(size_t)(n0 + ty + i * 8) * FQ + k0 + tx] = T[tx][ty + i * 8];
    } else {
        const int n0 = (blockIdx.x >> 3) * 32;
        const int yy = (blockIdx.x & 7) * 8 + blockIdx.y;   // 0..63
        const int ft = yy >> 3, h = yy & 7;
#pragma unroll
        for (int i = 0; i < 4; ++i) {
            int fl = ty + i * 8;
            T[fl][tx] = (f16)Wo[(size_t)((ft * 32 + fl) * 8 + h) * FQ + n0 + tx];
        }
        __syncthreads();
#pragma unroll
        for (int i = 0; i < 4; ++i)
            woT[(size_t)(n0 + ty + i * 8) * FH + h * 256 + ft * 32 + tx] = T[tx][ty + i * 8];
    }
}

// ---------------------------------------------------------------------------
// Swizzled staging, LDS row stride 64 f16 (BK=64 GEMM tiles).
// ---------------------------------------------------------------------------
__device__ __forceinline__ void stage_sw64(const f16* __restrict__ G, int ldg,
                                           int row0, int c0, f16* S,
                                           int nrows, int w, int lane) {
    const int rsub = lane >> 3;           // 0..7
    const int g    = (lane & 7) ^ (rsub & 7);
#pragma unroll
    for (int rI = w; rI < (nrows >> 3); rI += 4) {
        GLOAD_LDS16(G + (size_t)(row0 + rI * 8 + rsub) * ldg + c0 + g * 8,
                    S + rI * 512);
    }
}

// ---------------------------------------------------------------------------
// 128x128 MFMA tile, BK=64 swizzled staging. 4 waves 2x2 of 64x64.
// ---------------------------------------------------------------------------
__device__ __forceinline__ void gemm128_sw(const f16* __restrict__ A, int lda,
                                           const f16* __restrict__ Bt, int ldb,
                                           int kbeg, int kend, f16* As, f16* Bs,
                                           f32x4 acc[4][4], int row0, int col0) {
    const int t = threadIdx.x, lane = t & 63, w = t >> 6;
    const int wr = w >> 1, wc = w & 1;
    const int lrow = lane & 15, quad = lane >> 4;
    for (int k0 = kbeg; k0 < kend; k0 += 64) {
        __syncthreads();
        stage_sw64(A, lda, row0, k0, As, 128, w, lane);
        stage_sw64(Bt, ldb, col0, k0, Bs, 128, w, lane);
        __syncthreads();
#pragma unroll
        for (int kk = 0; kk < 2; ++kk) {
            f16x8 af[4], bf[4];
#pragma unroll
            for (int i = 0; i < 4; ++i) {
                int r = wr * 64 + i * 16 + lrow;
                af[i] = *(const f16x8*)&As[r * 64 + (((kk * 4 + quad) ^ (r & 7)) << 3)];
            }
#pragma unroll
            for (int j = 0; j < 4; ++j) {
                int r = wc * 64 + j * 16 + lrow;
                bf[j] = *(const f16x8*)&Bs[r * 64 + (((kk * 4 + quad) ^ (r & 7)) << 3)];
            }
#pragma unroll
            for (int i = 0; i < 4; ++i)
#pragma unroll
                for (int j = 0; j < 4; ++j)
                    acc[i][j] = __builtin_amdgcn_mfma_f32_16x16x32_f16(af[i], bf[j], acc[i][j], 0, 0, 0);
        }
    }
}

// ---------------------------------------------------------------------------
// Merged QKV projection with coalesced LDS-roundtrip epilogue.
// z=0 Q -> (b,h,s,f); z=1 K -> (b,h,s,f); z=2 V -> (b,h,f,s).
// ---------------------------------------------------------------------------
__global__ __launch_bounds__(256) void proj_mfma(const f16* __restrict__ xh,
                                                 const f16* __restrict__ wqT,
                                                 const f16* __restrict__ wkT,
                                                 const f16* __restrict__ wvT,
                                                 f16* __restrict__ qb,
                                                 f16* __restrict__ kb,
                                                 f16* __restrict__ vb) {
    const int z = blockIdx.z;
    const f16* WT = z == 0 ? wqT : (z == 1 ? wkT : wvT);
    f16* O        = z == 0 ? qb  : (z == 1 ? kb  : vb);
    __shared__ f16 smem[17408];          // As|Bs (16384) ; Es (17408) alias
    f16* As = smem;
    f16* Bs = smem + 8192;
    f32x4 acc[4][4] = {};
    const int row0 = blockIdx.y * 128, col0 = blockIdx.x * 128;
    gemm128_sw(xh, FQ, WT, FQ, 0, FQ, As, Bs, acc, row0, col0);

    __syncthreads();                     // As/Bs dead -> reuse as Es
    f16* Es = smem;                      // ld 136
    const int lane = threadIdx.x & 63, w = threadIdx.x >> 6;
    const int wr = w >> 1, wc = w & 1;
    const int lrow = lane & 15, quad = lane >> 4;
    if (z != 2) {
#pragma unroll
        for (int i = 0; i < 4; ++i)
#pragma unroll
            for (int rr = 0; rr < 4; ++rr) {
                int rl = 64 * wr + 16 * i + 4 * quad + rr;
#pragma unroll
                for (int j = 0; j < 4; ++j) {
                    int cc = 64 * wc + 16 * j + lrow;
                    Es[rl * 136 + (cc & 7) * 16 + (cc >> 3)] = (f16)acc[i][j][rr];
                }
            }
        __syncthreads();
        const int f0 = col0 >> 3;
#pragma unroll
        for (int it = 0; it < 4; ++it) {
            int c = it * 256 + threadIdx.x;
            int row = c >> 3, hh = c & 7;
            int gr = row0 + row, bbb = gr >> 10, s = gr & 1023;
            f16x8 v0 = *(const f16x8*)&Es[row * 136 + hh * 16];
            f16x8 v1 = *(const f16x8*)&Es[row * 136 + hh * 16 + 8];
            f16* dst = O + ((size_t)(bbb * 8 + hh) * SQ + s) * FQ + f0;
            *(f16x8*)dst = v0;
            *(f16x8*)(dst + 8) = v1;
        }
    } else {
#pragma unroll
        for (int i = 0; i < 4; ++i)
#pragma unroll
            for (int rr = 0; rr < 4; ++rr) {
                int rl = 64 * wr + 16 * i + 4 * quad + rr;
#pragma unroll
                for (int j = 0; j < 4; ++j) {
                    int cc = 64 * wc + 16 * j + lrow;
                    Es[cc * 136 + rl] = (f16)acc[i][j][rr];
                }
            }
        __syncthreads();
        const int bbb = row0 >> 10, s0 = row0 & 1023;
#pragma unroll
        for (int it = 0; it < 8; ++it) {
            int c = it * 256 + threadIdx.x;
            int cc = c >> 4, sc = c & 15;
            int hh = cc & 7, f = (col0 >> 3) + (cc >> 3);
            f16x8 v = *(const f16x8*)&Es[cc * 136 + sc * 8];
            *(f16x8*)(O + ((size_t)(bbb * 8 + hh) * FQ + f) * SQ + s0 + sc * 8) = v;
        }
    }
}

// ---------------------------------------------------------------------------
// Fused attention v9 — M=32 per wave (double the MFMA per LDS byte of v8b).
// Per block: 128 Q-rows of (b,h); wave w owns rows 32w..32w+32.
// Grid = 256 blocks = exactly 1 block/CU (4 waves), VGPR-heavy by design
// (launch_bounds(256,1): qf 64 + acc_o 128 + temps ~ 240 VGPR).
// j-tile = 32. Per iteration jt:
//   [__syncthreads]  <- drains K(jt),V(jt) (issued one FULL iteration ago)
//   issue K(jt+1), V(jt+1)   (global_load_lds, pinned)
//   QK: S(32x32) (32 MFMA, 16 B-reads) -> sigmoid (rcp/exp2)
//   -> wave-PRIVATE Ps (in-order LDS, NO barrier) -> 2 A-frag reads
//   PV: WV(32x256) += P(32x32) @ V^T (32 MFMA, 16 B-reads)
// 64 MFMA / 34 KB LDS per wave-iter (v8b: 32 / 33).
// LDS: KB 2x16K + VB 2x16K + Pw 4x2.5K = 75776 B.
// ---------------------------------------------------------------------------
__global__ __launch_bounds__(256, 1) void fused_attn(const f16* __restrict__ Qb,
                                                     const f16* __restrict__ Kb,
                                                     const f16* __restrict__ Vt,
                                                     f16* __restrict__ WV) {
    __shared__ f16 smem[37888];   // KB0 8192 | KB1 8192 | VB0 8192 | VB1 8192 | Pw 4x1280 (f16 units)
    const int t = threadIdx.x, lane = t & 63, w = t >> 6;
    const int lrow = lane & 15, quad = lane >> 4;
    f16* Pw = smem + 32768 + w * 1280;           // wave-private 32 x 40
    // XCD swizzle: 4 consecutive heads per XCD -> Q/K/V L2-resident per XCD.
    const int n = blockIdx.x;                    // 0..255
    const int xcd = n & 7, rest = n >> 3;        // rest 0..31
    const int bh = xcd * 4 + (rest & 3);
    const int strip = rest >> 2;                 // 0..7
    const int m0 = strip * 128;
    const int bb = bh >> 3, h = bh & 7;
    const f16* Qg = Qb + (size_t)bh * SQ * FQ;   // (s,f)
    const f16* Kg = Kb + (size_t)bh * SQ * FQ;   // (s,f)
    const f16* Vg = Vt + (size_t)bh * FQ * SQ;   // (f,s)

    // Q rows [m0+32w, +32) as A-fragments in registers (64 VGPR, loaded once).
    f16x8 qf[2][8];
#pragma unroll
    for (int mi = 0; mi < 2; ++mi)
#pragma unroll
        for (int ks = 0; ks < 8; ++ks)
            qf[mi][ks] = *(const f16x8*)(Qg + (size_t)(m0 + 32 * w + 16 * mi + lrow) * FQ
                                             + ks * 32 + quad * 8);

    // K staging geometry: 16 insts (4/wave), 2 rows x 32 granules each.
    // KB[r][p] holds source granule p^(r&7); read logical g at p = g^(r&7).
    const int krs = lane >> 5;                   // 0..1
    const int kgp = lane & 31;
    // V staging geometry: 16 insts (4/wave), 16 rows x 4 granules each.
    // VB[f][p] holds source granule p^((f>>1)&3); read at p = g^((f>>1)&3).
    const int vrs = lane >> 2;                   // 0..15
    const int vgp = lane & 3;

    // Prologue: issue K(0) -> KB0 and V(0) -> VB0.
#pragma unroll
    for (int i = 0; i < 4; ++i) {
        int rI = w + i * 4;
        int r = rI * 2 + krs;
        GLOAD_LDS16(Kg + (size_t)r * FQ + ((kgp ^ (r & 7)) << 3), smem + rI * 512);
    }
#pragma unroll
    for (int i = 0; i < 4; ++i) {
        int rI = w + i * 4;
        int f = rI * 16 + vrs;
        GLOAD_LDS16(Vg + (size_t)f * SQ + ((vgp ^ ((f >> 1) & 3)) << 3),
                    smem + 16384 + rI * 512);
    }

    f32x4 acc_o[2][16] = {};   // rows 32w+16mi+4quad+rr, f = 16nj+lrow

    for (int jt = 0; jt < 32; ++jt) {
        const int j0 = jt * 32;
        f16* KBc = (jt & 1) ? smem + 8192  : smem;
        f16* VBc = (jt & 1) ? smem + 24576 : smem + 16384;
        __syncthreads();                 // drains K(jt),V(jt): one full iter old
        // ---- issue K(jt+1), V(jt+1) into the other buffers ----
        if (jt < 31) {
            f16* KBn = (jt & 1) ? smem         : smem + 8192;
            f16* VBn = (jt & 1) ? smem + 16384 : smem + 24576;
#pragma unroll
            for (int i = 0; i < 4; ++i) {
                int rI = w + i * 4;
                int r = rI * 2 + krs;
                GLOAD_LDS16(Kg + (size_t)(j0 + 32 + r) * FQ + ((kgp ^ (r & 7)) << 3),
                            KBn + rI * 512);
            }
#pragma unroll
            for (int i = 0; i < 4; ++i) {
                int rI = w + i * 4;
                int f = rI * 16 + vrs;
                GLOAD_LDS16(Vg + (size_t)f * SQ + j0 + 32 + ((vgp ^ ((f >> 1) & 3)) << 3),
                            VBn + rI * 512);
            }
        }
        // ---- QK^T: S(32x32) rows 32w..+32, cols j0..+32; K-dim 256 ----
        f32x4 acc_s[2][2] = {};
#pragma unroll
        for (int ks = 0; ks < 8; ++ks) {
            f16x8 bf[2];
#pragma unroll
            for (int nj = 0; nj < 2; ++nj) {
                int rk = 16 * nj + lrow;
                bf[nj] = *(const f16x8*)&KBc[rk * 256 + (((ks * 4 + quad) ^ (rk & 7)) << 3)];
            }
#pragma unroll
            for (int mi = 0; mi < 2; ++mi)
#pragma unroll
                for (int nj = 0; nj < 2; ++nj)
                    acc_s[mi][nj] = __builtin_amdgcn_mfma_f32_16x16x32_f16(
                        qf[mi][ks], bf[nj], acc_s[mi][nj], 0, 0, 0);
        }
        // ---- sigmoid -> wave-private Ps (NO barrier: in-order own-wave LDS) ----
#pragma unroll
        for (int mi = 0; mi < 2; ++mi)
#pragma unroll
            for (int nj = 0; nj < 2; ++nj)
#pragma unroll
                for (int rr = 0; rr < 4; ++rr)
                    Pw[(16 * mi + 4 * quad + rr) * 40 + 16 * nj + lrow] =
                        (f16)SIG16(acc_s[mi][nj][rr]);
        // ---- P as A-frags; PV: WV(32x256) += P(32x32) @ V^T ----
        f16x8 ap[2];
#pragma unroll
        for (int mi = 0; mi < 2; ++mi)
            ap[mi] = *(const f16x8*)&Pw[(16 * mi + lrow) * 40 + quad * 8];
#pragma unroll
        for (int nj = 0; nj < 16; ++nj) {
            int f = 16 * nj + lrow;
            f16x8 bv = *(const f16x8*)&VBc[f * 32 + ((quad ^ ((f >> 1) & 3)) << 3)];
#pragma unroll
            for (int mi = 0; mi < 2; ++mi)
                acc_o[mi][nj] = __builtin_amdgcn_mfma_f32_16x16x32_f16(
                    ap[mi], bv, acc_o[mi][nj], 0, 0, 0);
        }
    }
    // ---- epilogue: LDS roundtrip -> 512 B contiguous rows ----
    __syncthreads();                             // smem dead
    f16* Es = smem;                              // 128 x 264 = 33792 f16 (fits 37888)
#pragma unroll
    for (int mi = 0; mi < 2; ++mi)
#pragma unroll
        for (int nj = 0; nj < 16; ++nj)
#pragma unroll
            for (int rr = 0; rr < 4; ++rr)
                Es[(32 * w + 16 * mi + 4 * quad + rr) * 264 + 16 * nj + lrow] =
                    (f16)acc_o[mi][nj][rr];
    __syncthreads();
#pragma unroll
    for (int it = 0; it < 16; ++it) {
        int c = it * 256 + t;
        int r = c >> 5, ck = c & 31;
        f16x8 v = *(const f16x8*)&Es[r * 264 + ck * 8];
        *(f16x8*)(WV + (size_t)(bb * SQ + m0 + r) * FH + h * 256 + ck * 8) = v;
    }
}

// ---------------------------------------------------------------------------
// out projection, split-K x8 over k = h*256+f. 128x128 tiles, grid (2,32,8).
// fp32 partials ALIASED onto dead qbuf/kbuf workspace (32 MB) -- no OOB.
// ---------------------------------------------------------------------------
__global__ __launch_bounds__(256) void out_mfma8(const f16* __restrict__ WVm,
                                                 const f16* __restrict__ WoT,
                                                 float* __restrict__ PP) {
    __shared__ f16 smem[16384];
    f16* As = smem;
    f16* Bs = smem + 8192;
    f32x4 acc[4][4] = {};
    const int row0 = blockIdx.y * 128, col0 = blockIdx.x * 128;
    const int kbeg = blockIdx.z * 256;
    gemm128_sw(WVm, FH, WoT, FH, kbeg, kbeg + 256, As, Bs, acc, row0, col0);

    float* P = PP + (size_t)blockIdx.z * SQ * 4 * FQ;
    const int lane = threadIdx.x & 63, w = threadIdx.x >> 6;
    const int wr = w >> 1, wc = w & 1;
    const int lrow = lane & 15, quad = lane >> 4;
#pragma unroll
    for (int i = 0; i < 4; ++i)
#pragma unroll
        for (int rr = 0; rr < 4; ++rr) {
            int gr = row0 + wr * 64 + i * 16 + quad * 4 + rr;
#pragma unroll
            for (int j = 0; j < 4; ++j) {
                int gc = col0 + wc * 64 + j * 16 + lrow;
                P[(size_t)gr * FQ + gc] = acc[i][j][rr];
            }
        }
}

__global__ __launch_bounds__(256) void reduce_relu8(const float* __restrict__ PP,
                                                    float* __restrict__ O) {
    int idx = (blockIdx.x * 256 + threadIdx.x) * 4;
    f32x4 s = *(const f32x4*)(PP + idx);
#pragma unroll
    for (int z = 1; z < 8; ++z)
        s += *(const f32x4*)(PP + (size_t)z * 1048576 + idx);
    f32x4 r = {fmaxf(s.x, 0.f), fmaxf(s.y, 0.f), fmaxf(s.z, 0.f), fmaxf(s.w, 0.f)};
    *(f32x4*)(O + idx) = r;
}

// ---------------------------------------------------------------------------
extern "C" void kernel_launch(void* const* d_in, const int* in_sizes, int n_in,
                              void* d_out, int out_size, void* d_ws, size_t ws_size,
                              hipStream_t stream) {
    const float* x  = (const float*)d_in[0];
    const float* Wq = (const float*)d_in[1];
    const float* Wk = (const float*)d_in[2];
    const float* Wv = (const float*)d_in[3];
    const float* Wo = (const float*)d_in[4];
    float* out = (float*)d_out;

    f16* ws = (f16*)d_ws;
    f16* xh    = ws;                       // 1,048,576
    f16* wqT   = xh    + 1048576;          // 524,288
    f16* wkT   = wqT   + 524288;
    f16* wvT   = wkT   + 524288;
    f16* woT   = wvT   + 524288;           // 524,288 (k permuted to h*256+f)
    f16* qbuf  = woT   + 524288;           // 8,388,608 (b,h,s,f)
    f16* kbuf  = qbuf  + 8388608;          // (b,h,s,f)
    f16* vbuf  = kbuf  + 8388608;          // (b,h,f,s)
    f16* wvbuf = vbuf  + 8388608;          // (b*s, h*256+f)
    // pp ALIASES qbuf+kbuf (dead after fused_attn): 8 x 1,048,576 fp32 = 32 MB.
    float* pp  = (float*)qbuf;

    dim3 blk(256);
    prep_kernel<<<dim3(64, 8, 5), blk, 0, stream>>>(x, Wq, Wk, Wv, Wo,
                                                    xh, wqT, wkT, wvT, woT);

    proj_mfma<<<dim3(16, 32, 3), blk, 0, stream>>>(xh, wqT, wkT, wvT, qbuf, kbuf, vbuf);

    fused_attn<<<dim3(256), blk, 0, stream>>>(qbuf, kbuf, vbuf, wvbuf);

    out_mfma8<<<dim3(2, 32, 8), blk, 0, stream>>>(wvbuf, woT, pp);
    reduce_relu8<<<dim3(1024), blk, 0, stream>>>(pp, out);
}